// Round 13
// baseline (2103.050 us; speedup 1.0000x reference)
//
#include <hip/hip_runtime.h>
#include <math.h>
#include <stdint.h>

typedef int v4i  __attribute__((ext_vector_type(4)));
typedef int v16i __attribute__((ext_vector_type(16)));

#define NTOK 8192
#define HID  4096
#define FFND 14336

typedef const __attribute__((address_space(1))) void* gp_t;
typedef __attribute__((address_space(3))) void*       lp_t;

#define BAR()      __builtin_amdgcn_s_barrier()
#define MEMFENCE() asm volatile("" ::: "memory")

// ---- pack int32 weights -> int8, all three matrices in one dispatch ----
__global__ __launch_bounds__(256) void k_pack3(
    const int* __restrict__ w1, const int* __restrict__ w3,
    const int* __restrict__ w2, int8_t* __restrict__ o1,
    int8_t* __restrict__ o3, int8_t* __restrict__ o2, int n4) {
  int i = blockIdx.x * 256 + threadIdx.x;
  if (i >= n4) return;
  const int* s = (blockIdx.y == 0) ? w1 : (blockIdx.y == 1) ? w3 : w2;
  int8_t*    d = (blockIdx.y == 0) ? o1 : (blockIdx.y == 1) ? o3 : o2;
  int4 v = reinterpret_cast<const int4*>(s)[i];
  reinterpret_cast<int*>(d)[i] =
      (v.x & 255) | ((v.y & 255) << 8) | ((v.z & 255) << 16) | ((v.w & 255) << 24);
}

// ---------------- quantize x: fp32 -> int8, 4 elems/thread ----------------
__global__ __launch_bounds__(256) void k_quant_x(
    const float* __restrict__ x, int8_t* __restrict__ q,
    const float* __restrict__ sp, int n4) {
  int i = blockIdx.x * 256 + threadIdx.x;
  if (i >= n4) return;
  float s = *sp;
  float4 v = reinterpret_cast<const float4*>(x)[i];
  int a = (int)rintf(v.x / s); a = a < -128 ? -128 : (a > 127 ? 127 : a);
  int b = (int)rintf(v.y / s); b = b < -128 ? -128 : (b > 127 ? 127 : b);
  int c = (int)rintf(v.z / s); c = c < -128 ? -128 : (c > 127 ? 127 : c);
  int d = (int)rintf(v.w / s); d = d < -128 ? -128 : (d > 127 ? 127 : d);
  reinterpret_cast<int*>(q)[i] =
      (a & 255) | ((b & 255) << 8) | ((c & 255) << 16) | ((d & 255) << 24);
}

// ---- stage one [ROWS][64B] int8 tile into LDS (XOR-swizzled, rule #21) ----
template <int ROWS, int NWAVES>
__device__ __forceinline__ void stage_tile(const int8_t* __restrict__ src,
                                           int ld, int8_t* lds,
                                           int wave, int lane) {
  constexpr int NSEG = ROWS / 16;
  constexpr int PER  = NSEG / NWAVES;
#pragma unroll
  for (int j = 0; j < PER; ++j) {
    const int seg  = wave * PER + j;
    const int o    = (seg << 10) + (lane << 4);
    const int row  = o >> 6;
    const int slot = (o >> 4) & 3;
    const int gs   = slot ^ ((row >> 1) & 3);
    const int8_t* g = src + (size_t)row * ld + (gs << 4);
    __builtin_amdgcn_global_load_lds((gp_t)g, (lp_t)(lds + (seg << 10)), 16, 0, 0);
  }
}

// read one 16B MFMA fragment (row, linear k-slot) with the inverse swizzle
__device__ __forceinline__ v4i frag16(const int8_t* lds, int row, int sl) {
  const int s2 = sl ^ ((row >> 1) & 3);
  return *reinterpret_cast<const v4i*>(lds + (row << 6) + (s2 << 4));
}

// ------- GEMM1: q1[T,H] x {w1,w3}[FFN,H]^T -> SwiGLU -> q2 int8 -------
// R6 geometry: 512 thr / 8 waves; tile 256x128 dual; per-wave 64x64 both.
// Edits: stage issued BEFORE reads (no alias-forced lgkmcnt(0) drain),
// NO setprio (it fences the MFMA cluster), XCD chunk-swizzled 1D grid.
__global__ __launch_bounds__(512, 2) void k_gemm1(
    const int8_t* __restrict__ q1, const int8_t* __restrict__ w1,
    const int8_t* __restrict__ w3, int8_t* __restrict__ q2,
    const float* __restrict__ w1sp, const float* __restrict__ w3sp,
    const float* __restrict__ a1sp, const float* __restrict__ a2sp) {
  __shared__ __align__(16) int8_t As[3][256 * 64];   // 48 KiB
  __shared__ __align__(16) int8_t B1s[3][128 * 64];  // 24 KiB
  __shared__ __align__(16) int8_t B3s[3][128 * 64];  // 24 KiB
  const int lane = threadIdx.x & 63;
  const int wave = threadIdx.x >> 6;   // 0..7
  const int wr = wave >> 1;            // 0..3 (M quadrant, 64 rows)
  const int wc = wave & 1;             // 0..1 (N half, 64 cols)
  const int r0 = lane & 31;
  // XCD chunk swizzle: grid 3584 (112 x 32), 3584 % 8 == 0 -> bijective
  const int id  = blockIdx.x;
  const int swz = (id & 7) * 448 + (id >> 3);
  const int mbase = (swz / 112) * 256;
  const int nbase = (swz % 112) * 128;
  const int8_t* Ap  = q1 + (size_t)mbase * HID;
  const int8_t* B1p = w1 + (size_t)nbase * HID;
  const int8_t* B3p = w3 + (size_t)nbase * HID;
  constexpr int NT = HID / 64;

  v16i acc1[2][2], acc3[2][2];
#pragma unroll
  for (int m = 0; m < 2; ++m)
#pragma unroll
    for (int n = 0; n < 2; ++n)
#pragma unroll
      for (int r = 0; r < 16; ++r) { acc1[m][n][r] = 0; acc3[m][n][r] = 0; }

  // prologue: stage K-tiles 0,1 (4 loads/wave/tile, FIFO)
#pragma unroll
  for (int t = 0; t < 2; ++t) {
    stage_tile<256, 8>(Ap  + t * 64, HID, As[t],  wave, lane);
    stage_tile<128, 8>(B1p + t * 64, HID, B1s[t], wave, lane);
    stage_tile<128, 8>(B3p + t * 64, HID, B3s[t], wave, lane);
  }

  int cur = 0;
  for (int kt = 0; kt < NT; ++kt) {
    // own loads of tile kt landed (tile kt+1's 4 may remain in flight)
    if (kt < NT - 1) asm volatile("s_waitcnt vmcnt(4)" ::: "memory");
    else             asm volatile("s_waitcnt vmcnt(0)" ::: "memory");
    BAR();       // tile kt in LDS everywhere; all waves consumed kt-1
    MEMFENCE();
    // stage kt+2 FIRST (write-then-read: no lgkm drain forced)
    const int nx2 = (cur >= 1) ? cur - 1 : 2;   // (kt+2)%3, last read at kt-1
    if (kt + 2 < NT) {
      stage_tile<256, 8>(Ap  + (kt + 2) * 64, HID, As[nx2],  wave, lane);
      stage_tile<128, 8>(B1p + (kt + 2) * 64, HID, B1s[nx2], wave, lane);
      stage_tile<128, 8>(B3p + (kt + 2) * 64, HID, B3s[nx2], wave, lane);
    }
    const int8_t* Ac  = As[cur];
    const int8_t* B1c = B1s[cur];
    const int8_t* B3c = B3s[cur];
    v4i a[2][2], b1[2][2], b3[2][2];
#pragma unroll
    for (int kk = 0; kk < 2; ++kk) {
      const int sl = kk * 2 + (lane >> 5);
      a[kk][0]  = frag16(Ac,  wr * 64 +      r0, sl);
      a[kk][1]  = frag16(Ac,  wr * 64 + 32 + r0, sl);
      b1[kk][0] = frag16(B1c, wc * 64 +      r0, sl);
      b1[kk][1] = frag16(B1c, wc * 64 + 32 + r0, sl);
      b3[kk][0] = frag16(B3c, wc * 64 +      r0, sl);
      b3[kk][1] = frag16(B3c, wc * 64 + 32 + r0, sl);
    }
    // MFMA cluster: no setprio, no pins -> compiler sinks counted lgkm waits
#pragma unroll
    for (int kk = 0; kk < 2; ++kk)
#pragma unroll
      for (int m = 0; m < 2; ++m)
#pragma unroll
        for (int n = 0; n < 2; ++n) {
          acc1[m][n] = __builtin_amdgcn_mfma_i32_32x32x32_i8(a[kk][m], b1[kk][n], acc1[m][n], 0, 0, 0);
          acc3[m][n] = __builtin_amdgcn_mfma_i32_32x32x32_i8(a[kk][m], b3[kk][n], acc3[m][n], 0, 0, 0);
        }
    cur = (cur == 2) ? 0 : cur + 1;
  }

  const float s1 = (*a1sp) * (*w1sp);
  const float s3 = (*a1sp) * (*w3sp);
  const float ia2 = 1.f / (*a2sp);
#pragma unroll
  for (int m = 0; m < 2; ++m)
#pragma unroll
    for (int n = 0; n < 2; ++n) {
      const int colg = nbase + wc * 64 + n * 32 + r0;
#pragma unroll
      for (int r = 0; r < 16; ++r) {
        const int rowg = mbase + wr * 64 + m * 32 +
                         (r & 3) + ((r >> 2) << 3) + ((lane >> 5) << 2);
        const float g = (float)acc1[m][n][r] * s1;
        const float u = (float)acc3[m][n][r] * s3;
        const float h = g * __builtin_amdgcn_rcpf(1.f + __expf(-g)) * u;
        float t = rintf(h * ia2);
        t = fminf(fmaxf(t, -128.f), 127.f);
        q2[(size_t)rowg * FFND + colg] = (int8_t)(int)t;
      }
    }
}

// ------- GEMM2: q2[T,FFN] x w2[HID,FFN]^T -> fp32 out -------
// R10 geometry: 256 thr / 4 waves (1 wave/SIMD); block 256x256; per-wave
// 128x128 (acc 256 AGPR). Same edits: stage-first, no setprio, XCD swizzle.
__global__ __launch_bounds__(256, 1) void k_gemm2(
    const int8_t* __restrict__ q2, const int8_t* __restrict__ w2,
    float* __restrict__ out,
    const float* __restrict__ w2sp, const float* __restrict__ a2sp) {
  __shared__ __align__(16) int8_t As[3][256 * 64];  // 48 KiB
  __shared__ __align__(16) int8_t Bs[3][256 * 64];  // 48 KiB
  const int lane = threadIdx.x & 63;
  const int wave = threadIdx.x >> 6;   // 0..3
  const int wr = wave >> 1;            // 0..1 (M half, 128 rows)
  const int wc = wave & 1;             // 0..1 (N half, 128 cols)
  const int r0 = lane & 31;
  // grid 512 (16 x 32), 512 % 8 == 0 -> bijective chunk swizzle
  const int id  = blockIdx.x;
  const int swz = (id & 7) * 64 + (id >> 3);
  const int mbase = (swz / 16) * 256;
  const int nbase = (swz % 16) * 256;
  const int8_t* Ap = q2 + (size_t)mbase * FFND;
  const int8_t* Bp = w2 + (size_t)nbase * FFND;
  constexpr int NT = FFND / 64;

  v16i acc[4][4];
#pragma unroll
  for (int m = 0; m < 4; ++m)
#pragma unroll
    for (int n = 0; n < 4; ++n)
#pragma unroll
      for (int r = 0; r < 16; ++r) acc[m][n][r] = 0;

#pragma unroll
  for (int t = 0; t < 2; ++t) {
    stage_tile<256, 4>(Ap + t * 64, FFND, As[t], wave, lane);
    stage_tile<256, 4>(Bp + t * 64, FFND, Bs[t], wave, lane);
  }

  int cur = 0;
  for (int kt = 0; kt < NT; ++kt) {
    if (kt < NT - 1) asm volatile("s_waitcnt vmcnt(8)" ::: "memory");
    else             asm volatile("s_waitcnt vmcnt(0)" ::: "memory");
    BAR();
    MEMFENCE();
    const int nx2 = (cur >= 1) ? cur - 1 : 2;
    if (kt + 2 < NT) {
      stage_tile<256, 4>(Ap + (kt + 2) * 64, FFND, As[nx2], wave, lane);
      stage_tile<256, 4>(Bp + (kt + 2) * 64, FFND, Bs[nx2], wave, lane);
    }
    const int8_t* Ac = As[cur];
    const int8_t* Bc = Bs[cur];
    v4i a[2][4], b[2][4];
#pragma unroll
    for (int kk = 0; kk < 2; ++kk) {
      const int sl = kk * 2 + (lane >> 5);
#pragma unroll
      for (int m = 0; m < 4; ++m)
        a[kk][m] = frag16(Ac, wr * 128 + m * 32 + r0, sl);
#pragma unroll
      for (int n = 0; n < 4; ++n)
        b[kk][n] = frag16(Bc, wc * 128 + n * 32 + r0, sl);
    }
#pragma unroll
    for (int kk = 0; kk < 2; ++kk)
#pragma unroll
      for (int m = 0; m < 4; ++m)
#pragma unroll
        for (int n = 0; n < 4; ++n)
          acc[m][n] = __builtin_amdgcn_mfma_i32_32x32x32_i8(a[kk][m], b[kk][n], acc[m][n], 0, 0, 0);
    cur = (cur == 2) ? 0 : cur + 1;
  }

  const float s = (*a2sp) * (*w2sp);
#pragma unroll
  for (int m = 0; m < 4; ++m)
#pragma unroll
    for (int n = 0; n < 4; ++n) {
      const int colg = nbase + wc * 128 + n * 32 + r0;
#pragma unroll
      for (int r = 0; r < 16; ++r) {
        const int rowg = mbase + wr * 128 + m * 32 +
                         (r & 3) + ((r >> 2) << 3) + ((lane >> 5) << 2);
        out[(size_t)rowg * HID + colg] = (float)acc[m][n][r] * s;
      }
    }
}

extern "C" void kernel_launch(void* const* d_in, const int* in_sizes, int n_in,
                              void* d_out, int out_size, void* d_ws, size_t ws_size,
                              hipStream_t stream) {
  const float* x    = (const float*)d_in[0];
  const int*   w1i  = (const int*)d_in[1];   // int8 values stored as int32
  const int*   w3i  = (const int*)d_in[2];
  const int*   w2i  = (const int*)d_in[3];
  const float* w1s  = (const float*)d_in[4];
  const float* w3s  = (const float*)d_in[5];
  const float* w2s  = (const float*)d_in[6];
  const float* a1s  = (const float*)d_in[7];
  const float* a2s  = (const float*)d_in[8];
  float* out = (float*)d_out;

  // workspace layout
  int8_t* q1  = (int8_t*)d_ws;                         // [NTOK][HID]    33.5 MB
  int8_t* q2  = q1 + (size_t)NTOK * HID;               // [NTOK][FFND]  117.4 MB
  int8_t* w1p = q2 + (size_t)NTOK * FFND;              // [FFN][HID]     58.7 MB
  int8_t* w3p = w1p + (size_t)FFND * HID;              //                58.7 MB
  int8_t* w2p = w3p + (size_t)FFND * HID;              // [HID][FFN]     58.7 MB

  const int wn4 = (int)((size_t)FFND * HID / 4);
  k_pack3<<<dim3(wn4 / 256, 3), 256, 0, stream>>>(w1i, w3i, w2i, w1p, w3p, w2p, wn4);

  const int n4 = NTOK * HID / 4;
  k_quant_x<<<n4 / 256, 256, 0, stream>>>(x, q1, a1s, n4);
  k_gemm1<<<3584, 512, 0, stream>>>(q1, w1p, w3p, q2, w1s, w3s, a1s, a2s);
  k_gemm2<<<512, 256, 0, stream>>>(q2, w2p, out, w2s, a2s);
}

// Round 14
// 1582.423 us; speedup vs baseline: 1.3290x; 1.3290x over previous
//
#include <hip/hip_runtime.h>
#include <math.h>
#include <stdint.h>

typedef int v4i  __attribute__((ext_vector_type(4)));
typedef int v16i __attribute__((ext_vector_type(16)));

#define NTOK 8192
#define HID  4096
#define FFND 14336

typedef const __attribute__((address_space(1))) void* gp_t;
typedef __attribute__((address_space(3))) void*       lp_t;

#define BAR()      __builtin_amdgcn_s_barrier()
#define SETPRIO(p) __builtin_amdgcn_s_setprio(p)
#define MEMFENCE() asm volatile("" ::: "memory")

// ---- pack int32 weights -> int8, all three matrices in one dispatch ----
__global__ __launch_bounds__(256) void k_pack3(
    const int* __restrict__ w1, const int* __restrict__ w3,
    const int* __restrict__ w2, int8_t* __restrict__ o1,
    int8_t* __restrict__ o3, int8_t* __restrict__ o2, int n4) {
  int i = blockIdx.x * 256 + threadIdx.x;
  if (i >= n4) return;
  const int* s = (blockIdx.y == 0) ? w1 : (blockIdx.y == 1) ? w3 : w2;
  int8_t*    d = (blockIdx.y == 0) ? o1 : (blockIdx.y == 1) ? o3 : o2;
  int4 v = reinterpret_cast<const int4*>(s)[i];
  reinterpret_cast<int*>(d)[i] =
      (v.x & 255) | ((v.y & 255) << 8) | ((v.z & 255) << 16) | ((v.w & 255) << 24);
}

// ---------------- quantize x: fp32 -> int8, 4 elems/thread ----------------
__global__ __launch_bounds__(256) void k_quant_x(
    const float* __restrict__ x, int8_t* __restrict__ q,
    const float* __restrict__ sp, int n4) {
  int i = blockIdx.x * 256 + threadIdx.x;
  if (i >= n4) return;
  float s = *sp;
  float4 v = reinterpret_cast<const float4*>(x)[i];
  int a = (int)rintf(v.x / s); a = a < -128 ? -128 : (a > 127 ? 127 : a);
  int b = (int)rintf(v.y / s); b = b < -128 ? -128 : (b > 127 ? 127 : b);
  int c = (int)rintf(v.z / s); c = c < -128 ? -128 : (c > 127 ? 127 : c);
  int d = (int)rintf(v.w / s); d = d < -128 ? -128 : (d > 127 ? 127 : d);
  reinterpret_cast<int*>(q)[i] =
      (a & 255) | ((b & 255) << 8) | ((c & 255) << 16) | ((d & 255) << 24);
}

// ---- stage one [ROWS][64B] int8 tile into LDS (XOR-swizzled, rule #21) ----
template <int ROWS, int NWAVES>
__device__ __forceinline__ void stage_tile(const int8_t* __restrict__ src,
                                           int ld, int8_t* lds,
                                           int wave, int lane) {
  constexpr int NSEG = ROWS / 16;
  constexpr int PER  = NSEG / NWAVES;
#pragma unroll
  for (int j = 0; j < PER; ++j) {
    const int seg  = wave * PER + j;
    const int o    = (seg << 10) + (lane << 4);
    const int row  = o >> 6;
    const int slot = (o >> 4) & 3;
    const int gs   = slot ^ ((row >> 1) & 3);
    const int8_t* g = src + (size_t)row * ld + (gs << 4);
    __builtin_amdgcn_global_load_lds((gp_t)g, (lp_t)(lds + (seg << 10)), 16, 0, 0);
  }
}

// read one 16B MFMA fragment (row, linear k-slot) with the inverse swizzle
__device__ __forceinline__ v4i frag16(const int8_t* lds, int row, int sl) {
  const int s2 = sl ^ ((row >> 1) & 3);
  return *reinterpret_cast<const v4i*>(lds + (row << 6) + (s2 << 4));
}

// ------- GEMM1 (exact Round-6 champion: 940us @ MfmaUtil 51%) -------
// 512 thr / 8 waves; tile 256x128 dual (gate+up); depth-3, 96 KiB, 1 block/CU.
// Order per K-tile: vmcnt(4) -> BAR -> reads(12) -> stage(kt+2) -> setprio MFMA.
__global__ __launch_bounds__(512, 2) void k_gemm1(
    const int8_t* __restrict__ q1, const int8_t* __restrict__ w1,
    const int8_t* __restrict__ w3, int8_t* __restrict__ q2,
    const float* __restrict__ w1sp, const float* __restrict__ w3sp,
    const float* __restrict__ a1sp, const float* __restrict__ a2sp) {
  __shared__ __align__(16) int8_t As[3][256 * 64];   // 48 KiB
  __shared__ __align__(16) int8_t B1s[3][128 * 64];  // 24 KiB
  __shared__ __align__(16) int8_t B3s[3][128 * 64];  // 24 KiB
  const int lane = threadIdx.x & 63;
  const int wave = threadIdx.x >> 6;   // 0..7
  const int wr = wave >> 1;            // 0..3 (M quadrant, 64 rows)
  const int wc = wave & 1;             // 0..1 (N half, 64 cols)
  const int r0 = lane & 31;
  const int mbase = blockIdx.y * 256;
  const int nbase = blockIdx.x * 128;
  const int8_t* Ap  = q1 + (size_t)mbase * HID;
  const int8_t* B1p = w1 + (size_t)nbase * HID;
  const int8_t* B3p = w3 + (size_t)nbase * HID;
  constexpr int NT = HID / 64;

  v16i acc1[2][2], acc3[2][2];
#pragma unroll
  for (int m = 0; m < 2; ++m)
#pragma unroll
    for (int n = 0; n < 2; ++n)
#pragma unroll
      for (int r = 0; r < 16; ++r) { acc1[m][n][r] = 0; acc3[m][n][r] = 0; }

  // prologue: issue K-tiles 0 and 1 (4 loads per wave per tile, FIFO)
#pragma unroll
  for (int t = 0; t < 2; ++t) {
    stage_tile<256, 8>(Ap  + t * 64, HID, As[t],  wave, lane);
    stage_tile<128, 8>(B1p + t * 64, HID, B1s[t], wave, lane);
    stage_tile<128, 8>(B3p + t * 64, HID, B3s[t], wave, lane);
  }

  int cur = 0;
  for (int kt = 0; kt < NT; ++kt) {
    if (kt < NT - 1) asm volatile("s_waitcnt vmcnt(4)" ::: "memory");
    else             asm volatile("s_waitcnt vmcnt(0)" ::: "memory");
    BAR();       // tile kt fully in LDS; all waves consumed tile kt-1
    MEMFENCE();
    const int8_t* Ac  = As[cur];
    const int8_t* B1c = B1s[cur];
    const int8_t* B3c = B3s[cur];
    // issue ALL fragment reads for this K-tile (12 ds_read_b128)
    v4i a[2][2], b1[2][2], b3[2][2];
#pragma unroll
    for (int kk = 0; kk < 2; ++kk) {
      const int sl = kk * 2 + (lane >> 5);
      a[kk][0]  = frag16(Ac,  wr * 64 +      r0, sl);
      a[kk][1]  = frag16(Ac,  wr * 64 + 32 + r0, sl);
      b1[kk][0] = frag16(B1c, wc * 64 +      r0, sl);
      b1[kk][1] = frag16(B1c, wc * 64 + 32 + r0, sl);
      b3[kk][0] = frag16(B3c, wc * 64 +      r0, sl);
      b3[kk][1] = frag16(B3c, wc * 64 + 32 + r0, sl);
    }
    // prefetch K-tile kt+2 (buf last read at kt-1 -> safe post-barrier)
    const int nx2 = (cur >= 1) ? cur - 1 : 2;
    if (kt + 2 < NT) {
      stage_tile<256, 8>(Ap  + (kt + 2) * 64, HID, As[nx2],  wave, lane);
      stage_tile<128, 8>(B1p + (kt + 2) * 64, HID, B1s[nx2], wave, lane);
      stage_tile<128, 8>(B3p + (kt + 2) * 64, HID, B3s[nx2], wave, lane);
    }
    SETPRIO(1);
#pragma unroll
    for (int kk = 0; kk < 2; ++kk)
#pragma unroll
      for (int m = 0; m < 2; ++m)
#pragma unroll
        for (int n = 0; n < 2; ++n) {
          acc1[m][n] = __builtin_amdgcn_mfma_i32_32x32x32_i8(a[kk][m], b1[kk][n], acc1[m][n], 0, 0, 0);
          acc3[m][n] = __builtin_amdgcn_mfma_i32_32x32x32_i8(a[kk][m], b3[kk][n], acc3[m][n], 0, 0, 0);
        }
    SETPRIO(0);
    cur = (cur == 2) ? 0 : cur + 1;
  }

  const float s1 = (*a1sp) * (*w1sp);
  const float s3 = (*a1sp) * (*w3sp);
  const float ia2 = 1.f / (*a2sp);
#pragma unroll
  for (int m = 0; m < 2; ++m)
#pragma unroll
    for (int n = 0; n < 2; ++n) {
      const int colg = nbase + wc * 64 + n * 32 + r0;
#pragma unroll
      for (int r = 0; r < 16; ++r) {
        const int rowg = mbase + wr * 64 + m * 32 +
                         (r & 3) + ((r >> 2) << 3) + ((lane >> 5) << 2);
        const float g = (float)acc1[m][n][r] * s1;
        const float u = (float)acc3[m][n][r] * s3;
        const float h = g * __builtin_amdgcn_rcpf(1.f + __expf(-g)) * u;
        float t = rintf(h * ia2);
        t = fminf(fmaxf(t, -128.f), 127.f);
        q2[(size_t)rowg * FFND + colg] = (int8_t)(int)t;
      }
    }
}

// ------- GEMM2 (exact Round-10 champion: ~390us) -------
// 256 thr / 4 waves (1 wave/SIMD); block 256x256; per-wave 128x128
// (acc 256 AGPR); depth-3 (96 KiB); vmcnt(8); reads -> stage -> setprio MFMA.
__global__ __launch_bounds__(256, 1) void k_gemm2(
    const int8_t* __restrict__ q2, const int8_t* __restrict__ w2,
    float* __restrict__ out,
    const float* __restrict__ w2sp, const float* __restrict__ a2sp) {
  __shared__ __align__(16) int8_t As[3][256 * 64];  // 48 KiB
  __shared__ __align__(16) int8_t Bs[3][256 * 64];  // 48 KiB
  const int lane = threadIdx.x & 63;
  const int wave = threadIdx.x >> 6;   // 0..3
  const int wr = wave >> 1;            // 0..1 (M half, 128 rows)
  const int wc = wave & 1;             // 0..1 (N half, 128 cols)
  const int r0 = lane & 31;
  const int mbase = blockIdx.y * 256;
  const int nbase = blockIdx.x * 256;
  const int8_t* Ap = q2 + (size_t)mbase * FFND;
  const int8_t* Bp = w2 + (size_t)nbase * FFND;
  constexpr int NT = FFND / 64;

  v16i acc[4][4];
#pragma unroll
  for (int m = 0; m < 4; ++m)
#pragma unroll
    for (int n = 0; n < 4; ++n)
#pragma unroll
      for (int r = 0; r < 16; ++r) acc[m][n][r] = 0;

#pragma unroll
  for (int t = 0; t < 2; ++t) {
    stage_tile<256, 4>(Ap + t * 64, FFND, As[t], wave, lane);
    stage_tile<256, 4>(Bp + t * 64, FFND, Bs[t], wave, lane);
  }

  int cur = 0;
  for (int kt = 0; kt < NT; ++kt) {
    if (kt < NT - 1) asm volatile("s_waitcnt vmcnt(8)" ::: "memory");
    else             asm volatile("s_waitcnt vmcnt(0)" ::: "memory");
    BAR();
    MEMFENCE();
    const int8_t* Ac = As[cur];
    const int8_t* Bc = Bs[cur];
    v4i a[2][4], b[2][4];
#pragma unroll
    for (int kk = 0; kk < 2; ++kk) {
      const int sl = kk * 2 + (lane >> 5);
#pragma unroll
      for (int m = 0; m < 4; ++m)
        a[kk][m] = frag16(Ac, wr * 128 + m * 32 + r0, sl);
#pragma unroll
      for (int n = 0; n < 4; ++n)
        b[kk][n] = frag16(Bc, wc * 128 + n * 32 + r0, sl);
    }
    const int nx2 = (cur >= 1) ? cur - 1 : 2;
    if (kt + 2 < NT) {
      stage_tile<256, 4>(Ap + (kt + 2) * 64, FFND, As[nx2], wave, lane);
      stage_tile<256, 4>(Bp + (kt + 2) * 64, FFND, Bs[nx2], wave, lane);
    }
    SETPRIO(1);
#pragma unroll
    for (int kk = 0; kk < 2; ++kk)
#pragma unroll
      for (int m = 0; m < 4; ++m)
#pragma unroll
        for (int n = 0; n < 4; ++n)
          acc[m][n] = __builtin_amdgcn_mfma_i32_32x32x32_i8(a[kk][m], b[kk][n], acc[m][n], 0, 0, 0);
    SETPRIO(0);
    cur = (cur == 2) ? 0 : cur + 1;
  }

  const float s = (*a2sp) * (*w2sp);
#pragma unroll
  for (int m = 0; m < 4; ++m)
#pragma unroll
    for (int n = 0; n < 4; ++n) {
      const int colg = nbase + wc * 128 + n * 32 + r0;
#pragma unroll
      for (int r = 0; r < 16; ++r) {
        const int rowg = mbase + wr * 128 + m * 32 +
                         (r & 3) + ((r >> 2) << 3) + ((lane >> 5) << 2);
        out[(size_t)rowg * HID + colg] = (float)acc[m][n][r] * s;
      }
    }
}

extern "C" void kernel_launch(void* const* d_in, const int* in_sizes, int n_in,
                              void* d_out, int out_size, void* d_ws, size_t ws_size,
                              hipStream_t stream) {
  const float* x    = (const float*)d_in[0];
  const int*   w1i  = (const int*)d_in[1];   // int8 values stored as int32
  const int*   w3i  = (const int*)d_in[2];
  const int*   w2i  = (const int*)d_in[3];
  const float* w1s  = (const float*)d_in[4];
  const float* w3s  = (const float*)d_in[5];
  const float* w2s  = (const float*)d_in[6];
  const float* a1s  = (const float*)d_in[7];
  const float* a2s  = (const float*)d_in[8];
  float* out = (float*)d_out;

  // workspace layout
  int8_t* q1  = (int8_t*)d_ws;                         // [NTOK][HID]    33.5 MB
  int8_t* q2  = q1 + (size_t)NTOK * HID;               // [NTOK][FFND]  117.4 MB
  int8_t* w1p = q2 + (size_t)NTOK * FFND;              // [FFN][HID]     58.7 MB
  int8_t* w3p = w1p + (size_t)FFND * HID;              //                58.7 MB
  int8_t* w2p = w3p + (size_t)FFND * HID;              // [HID][FFN]     58.7 MB

  const int wn4 = (int)((size_t)FFND * HID / 4);
  k_pack3<<<dim3(wn4 / 256, 3), 256, 0, stream>>>(w1i, w3i, w2i, w1p, w3p, w2p, wn4);

  const int n4 = NTOK * HID / 4;
  k_quant_x<<<n4 / 256, 256, 0, stream>>>(x, q1, a1s, n4);
  k_gemm1<<<dim3(FFND / 128, NTOK / 256), 512, 0, stream>>>(
      q1, w1p, w3p, q2, w1s, w3s, a1s, a2s);
  k_gemm2<<<dim3(HID / 256, NTOK / 256), 256, 0, stream>>>(
      q2, w2p, out, w2s, a2s);
}